// Round 8
// baseline (710.329 us; speedup 1.0000x reference)
//
#include <hip/hip_runtime.h>
#include <hip/hip_bf16.h>

#define N_TOK 8192
#define HD    2048
#define NE    8
#define FF    1024

using f32x4  = __attribute__((ext_vector_type(4))) float;
using bf16x8 = __attribute__((ext_vector_type(8))) __bf16;

__device__ __forceinline__ unsigned short f2bf(float f) {
  unsigned u = __float_as_uint(f);
  u += 0x7FFFu + ((u >> 16) & 1u);   // RTNE (inputs are finite/normal)
  return (unsigned short)(u >> 16);
}

__device__ __forceinline__ void gl_lds16(const void* g, void* l) {
  __builtin_amdgcn_global_load_lds((__attribute__((address_space(1))) void*)g,
                                   (__attribute__((address_space(3))) void*)l,
                                   16, 0, 0);
}

#define WAIT8_BAR() do {                                      \
    asm volatile("s_waitcnt vmcnt(8)" ::: "memory");          \
    __builtin_amdgcn_s_barrier();                             \
    __builtin_amdgcn_sched_barrier(0);                        \
  } while (0)

// ---- tiled transpose + convert: in[z][R][C] fp32 -> out[z*out_z + c*ostride + r] bf16 ----
__global__ void k_tconv(const float* __restrict__ in, unsigned short* __restrict__ out,
                        int R, int C, size_t in_z, size_t out_z, size_t ostride) {
  __shared__ float tile[32][33];
  const int z = blockIdx.z;
  const int c0 = blockIdx.x * 32, r0 = blockIdx.y * 32;
  const int tx = threadIdx.x, ty = threadIdx.y;
  const float* ip = in + (size_t)z * in_z;
  unsigned short* op = out + (size_t)z * out_z;
  #pragma unroll
  for (int i = ty; i < 32; i += 8)
    tile[i][tx] = ip[(size_t)(r0 + i) * C + (c0 + tx)];
  __syncthreads();
  #pragma unroll
  for (int i = ty; i < 32; i += 8)
    op[(size_t)(c0 + i) * ostride + (r0 + tx)] = f2bf(tile[tx][i]);
}

// ---- router: w = relu(x @ W_router), fp32 exact; also emits x in bf16. ----
__global__ void k_router(const float* __restrict__ x, const float* __restrict__ Wr,
                         float* __restrict__ w, float* __restrict__ rout,
                         unsigned short* __restrict__ xb) {
  const int lane = threadIdx.x & 63, wv = threadIdx.x >> 6;
  const int n = blockIdx.x * 4 + wv;
  const float* xr = x + (size_t)n * HD + lane * 32;
  unsigned short* xbr = xb + (size_t)n * HD + lane * 32;
  const float* wbase = Wr + (size_t)lane * 32 * NE;
  float acc[8];
  #pragma unroll
  for (int e = 0; e < 8; ++e) acc[e] = 0.f;
  #pragma unroll
  for (int kk = 0; kk < 32; kk += 4) {
    float4 xv = *reinterpret_cast<const float4*>(xr + kk);
    ushort4 o;
    o.x = f2bf(xv.x); o.y = f2bf(xv.y); o.z = f2bf(xv.z); o.w = f2bf(xv.w);
    *reinterpret_cast<ushort4*>(xbr + kk) = o;
    #pragma unroll
    for (int t = 0; t < 4; ++t) {
      const float* wrow = wbase + (kk + t) * 8;
      float4 w0 = *reinterpret_cast<const float4*>(wrow);
      float4 w1 = *reinterpret_cast<const float4*>(wrow + 4);
      float xs = (t == 0) ? xv.x : (t == 1) ? xv.y : (t == 2) ? xv.z : xv.w;
      acc[0] += xs * w0.x; acc[1] += xs * w0.y; acc[2] += xs * w0.z; acc[3] += xs * w0.w;
      acc[4] += xs * w1.x; acc[5] += xs * w1.y; acc[6] += xs * w1.z; acc[7] += xs * w1.w;
    }
  }
  #pragma unroll
  for (int off = 32; off; off >>= 1) {
    #pragma unroll
    for (int e = 0; e < 8; ++e) acc[e] += __shfl_down(acc[e], off);
  }
  if (lane == 0) {
    #pragma unroll
    for (int e = 0; e < 8; ++e) {
      float v = acc[e] > 0.f ? acc[e] : 0.f;
      w[n * 8 + e] = v;
      rout[n * 8 + e] = v;
    }
  }
}

// ---- per-expert stable compaction: idx[e][0..Me) = tokens with w>0, pad to 256-mult ----
__global__ void k_compact(const float* __restrict__ w, int* __restrict__ idx,
                          int* __restrict__ cnt) {
  const int e = blockIdx.x;
  __shared__ int base;
  __shared__ int scan[4];
  if (threadIdx.x == 0) base = 0;
  __syncthreads();
  const int lane = threadIdx.x & 63, wvi = threadIdx.x >> 6;
  for (int c0 = 0; c0 < N_TOK; c0 += 256) {
    const int n = c0 + threadIdx.x;
    const bool act = w[n * 8 + e] > 0.f;
    unsigned long long m = __ballot(act);
    const int pre  = __popcll(m & ((1ull << lane) - 1ull));
    if (lane == 0) scan[wvi] = __popcll(m);
    __syncthreads();
    int woff = 0;
    #pragma unroll
    for (int i = 0; i < 4; ++i) if (i < wvi) woff += scan[i];
    const int tot = scan[0] + scan[1] + scan[2] + scan[3];
    if (act) idx[e * N_TOK + base + woff + pre] = n;
    __syncthreads();
    if (threadIdx.x == 0) base += tot;
    __syncthreads();
  }
  const int M = base;
  if (threadIdx.x == 0) cnt[e] = M;
  const int Mpad = (M + 255) & ~255;
  for (int i = M + threadIdx.x; i < Mpad; i += 256) idx[e * N_TOK + i] = 0;
}

// =======================================================================
// GEMM1: fused gate+up on COMPACTED tokens, 256x128 tile, BK=64 as two
// 32-col halves ([rows][64B] compact blocks), 2-dbuf, counted vmcnt(8)
// (never 0 in loop), 64B-row XOR swizzle, setprio MFMA clusters.
// Epilogue silu(g)*u*w scattered to original A2 token rows (bf16).
// LDS: A 2x2x16K=64K @0; Bg 2x2x8K=32K @64K; Bu 32K @96K. Total 128K.
// =======================================================================
#define G1_MFMA(accM, barr) do {                                                 \
    __builtin_amdgcn_s_setprio(1);                                               \
    _Pragma("unroll")                                                            \
    for (int i = 0; i < 4; ++i) {                                                \
      _Pragma("unroll")                                                          \
      for (int j = 0; j < 4; ++j)                                                \
        accM[i][j] = __builtin_amdgcn_mfma_f32_16x16x32_bf16(av_[i], (barr)[j], accM[i][j], 0,0,0); \
    }                                                                            \
    __builtin_amdgcn_s_setprio(0);                                               \
  } while (0)

#define G1_ST_A(koff, base) do {                                                 \
    gl_lds16(aP0 + (koff), (base) + wv * 1024);                                  \
    gl_lds16(aP1 + (koff), (base) + (wv + 8) * 1024);                            \
  } while (0)
#define G1_ST_B(koff, bgb, bub) do {                                             \
    gl_lds16(gBg + bOff + (koff), (bgb) + wv * 1024);                            \
    gl_lds16(gBu + bOff + (koff), (bub) + wv * 1024);                            \
  } while (0)

#define G1_HALF(rsl, hh, ISSUE_B) do {                                           \
    const char* Ab_ = As  + (rsl) * 32768 + (hh) * 16384 + aoff;                 \
    const char* Bg_ = Bgs + (rsl) * 16384 + (hh) * 8192 + boff;                  \
    const char* Bu_ = Bus + (rsl) * 16384 + (hh) * 8192 + boff;                  \
    bf16x8 av_[4], bb_[4];                                                       \
    _Pragma("unroll")                                                            \
    for (int i = 0; i < 4; ++i) av_[i] = *(const bf16x8*)(Ab_ + i * 1024);       \
    _Pragma("unroll")                                                            \
    for (int j = 0; j < 4; ++j) bb_[j] = *(const bf16x8*)(Bg_ + j * 1024);       \
    G1_MFMA(ag, bb_);                                                            \
    ISSUE_B;                                                                     \
    _Pragma("unroll")                                                            \
    for (int j = 0; j < 4; ++j) bb_[j] = *(const bf16x8*)(Bu_ + j * 1024);       \
    G1_MFMA(au, bb_);                                                            \
  } while (0)

__global__ void __launch_bounds__(512, 2) k_gemm1(
    const unsigned short* __restrict__ xb,
    const unsigned short* __restrict__ Wg,
    const unsigned short* __restrict__ Wu,
    const float* __restrict__ w,
    const int* __restrict__ idx,
    const int* __restrict__ cnt,
    unsigned short* __restrict__ A2,
    int e0, int k2g, int nwg) {
  extern __shared__ char lds[];
  char* As  = lds;                  // [2 dbuf][2 half][256][64B]
  char* Bgs = lds + 65536;          // [2][2][128][64B]
  char* Bus = lds + 98304;
  const int tid = threadIdx.x;
  const int l = tid & 63, wv = tid >> 6;

  // XCD-chunk bijective swizzle; 256 blocks/expert = 8f x 32y, 2f x 8y sub-chunks
  const int h = blockIdx.x;
  const int chunk = nwg >> 3;
  const int L = (h & 7) * chunk + (h >> 3);
  const int eloc = L >> 8;
  const int e = e0 + eloc;
  const int idxq = L & 255;
  const int sub = idxq >> 5;
  const int f = ((sub & 1) << 2) | ((idxq >> 3) & 3);
  const int y = ((sub >> 1) << 3) | (idxq & 7);
  const int bm = y << 8;
  const int bf = f << 7;
  const int wr = wv >> 1, wc = wv & 1;     // 4M x 2N waves

  const int Me = cnt[e];
  if (bm >= Me) return;
  const int* idxe = idx + e * N_TOK;

  const unsigned short* gBg = Wg + ((size_t)e * FF + bf) * HD;
  const unsigned short* gBu = Wu + ((size_t)e * FF + bf) * HD;

  // 64B-row swizzle: stage src col unit = (l&3)^((l>>3)&3); read slot = kc4^((row>>1)&3)
  const int scolE = (((l & 3) ^ ((l >> 3) & 3)) << 3);   // elements
  const int fr  = l & 15;
  const int cph = (((l >> 4) ^ ((fr >> 1) & 3)) << 4);   // bytes
  const int aoff = (wr * 64 + fr) * 64 + cph;
  const int boff = (wc * 64 + fr) * 64 + cph;

  // per-thread staging bases (A gathered via compacted index; 16-row chunks)
  const unsigned short* aP0 = xb + (size_t)idxe[bm + wv * 16 + (l >> 2)] * HD + scolE;
  const unsigned short* aP1 = xb + (size_t)idxe[bm + (wv + 8) * 16 + (l >> 2)] * HD + scolE;
  const size_t bOff = (size_t)(wv * 16 + (l >> 2)) * HD + scolE;

  f32x4 ag[4][4], au[4][4];
  const f32x4 zero = {0.f, 0.f, 0.f, 0.f};
  #pragma unroll
  for (int i = 0; i < 4; ++i) {
    #pragma unroll
    for (int j = 0; j < 4; ++j) { ag[i][j] = zero; au[i][j] = zero; }
  }

  // prologue: (0,0) (0,1) (1,0) = 12 issues/thread; keep last 8 in flight
  G1_ST_A(0,  As);
  G1_ST_B(0,  Bgs, Bus);
  G1_ST_A(32, As + 16384);
  G1_ST_B(32, Bgs + 8192, Bus + 8192);
  G1_ST_A(64, As + 32768);
  G1_ST_B(64, Bgs + 16384, Bus + 16384);
  WAIT8_BAR();

  const int NT = HD / 64;   // 32
  for (int t = 0; t < NT; ++t) {
    const int rs = t & 1, sw = rs ^ 1;
    const int kn1 = ((t + 1 < NT) ? t + 1 : NT - 1) * 64;
    const int kn2 = ((t + 2 < NT) ? t + 2 : NT - 1) * 64;
    // ---- half 0: compute (t,0); issue (t+1,1) ----
    G1_ST_A(kn1 + 32, As + sw * 32768 + 16384);
    G1_HALF(rs, 0, G1_ST_B(kn1 + 32, Bgs + sw * 16384 + 8192, Bus + sw * 16384 + 8192));
    WAIT8_BAR();   // retires (t,1); leaves (t+1,0),(t+1,1)... (8)
    // ---- half 1: compute (t,1); issue (t+2,0) into slot rs ----
    G1_ST_A(kn2, As + rs * 32768);
    G1_HALF(rs, 1, G1_ST_B(kn2, Bgs + rs * 16384, Bus + rs * 16384));
    WAIT8_BAR();   // retires (t+1,0)
  }

  // epilogue: silu(g)*u*w -> A2 (scattered to original token rows).
  const int orow = (l >> 4) << 2;
  #pragma unroll
  for (int am = 0; am < 4; ++am) {
    #pragma unroll
    for (int rr = 0; rr < 4; ++rr) {
      const int cm = bm + wr * 64 + am * 16 + orow + rr;
      const int n = idxe[cm];
      const float wn = w[n * 8 + e];
      size_t obase = (size_t)n * k2g + (size_t)eloc * FF + bf + wc * 64 + fr;
      #pragma unroll
      for (int j = 0; j < 4; ++j) {
        const float g = ag[am][j][rr];
        const float u = au[am][j][rr];
        const float s = g / (1.f + __expf(-g));
        A2[obase + j * 16] = f2bf(s * u * wn);
      }
    }
  }
}

// =======================================================================
// GEMM2 (dense): out(+)= A2 @ Wd. 256x256 tile, BK=64 as two halves,
// waves 2M x 4N (per-wave 128x64), same counted-vmcnt(8) pipeline.
// LDS: A 2x2x16K=64K @0; B 2x2x16K=64K @64K. Total 128K.
// =======================================================================
#define G2_ST_A(koff, base) do {                                                 \
    gl_lds16(gA + aOff0 + (koff), (base) + wv * 1024);                           \
    gl_lds16(gA + aOff1 + (koff), (base) + (wv + 8) * 1024);                     \
  } while (0)
#define G2_ST_B(koff, base) do {                                                 \
    gl_lds16(gB + bOff0 + (koff), (base) + wv * 1024);                           \
    gl_lds16(gB + bOff1 + (koff), (base) + (wv + 8) * 1024);                     \
  } while (0)

#define G2_HALF(rsl, hh, ISSUE_B) do {                                           \
    const char* Ab_ = As + (rsl) * 32768 + (hh) * 16384 + aoff;                  \
    const char* Bb_ = Bs + (rsl) * 32768 + (hh) * 16384 + boff;                  \
    bf16x8 av_[8], bv_[4];                                                       \
    _Pragma("unroll")                                                            \
    for (int i = 0; i < 8; ++i) av_[i] = *(const bf16x8*)(Ab_ + i * 1024);       \
    _Pragma("unroll")                                                            \
    for (int j = 0; j < 4; ++j) bv_[j] = *(const bf16x8*)(Bb_ + j * 1024);       \
    __builtin_amdgcn_s_setprio(1);                                               \
    _Pragma("unroll")                                                            \
    for (int i = 0; i < 4; ++i) {                                                \
      _Pragma("unroll")                                                          \
      for (int j = 0; j < 4; ++j)                                                \
        acc[i][j] = __builtin_amdgcn_mfma_f32_16x16x32_bf16(av_[i], bv_[j], acc[i][j], 0,0,0); \
    }                                                                            \
    __builtin_amdgcn_s_setprio(0);                                               \
    ISSUE_B;                                                                     \
    __builtin_amdgcn_s_setprio(1);                                               \
    _Pragma("unroll")                                                            \
    for (int i = 4; i < 8; ++i) {                                                \
      _Pragma("unroll")                                                          \
      for (int j = 0; j < 4; ++j)                                                \
        acc[i][j] = __builtin_amdgcn_mfma_f32_16x16x32_bf16(av_[i], bv_[j], acc[i][j], 0,0,0); \
    }                                                                            \
    __builtin_amdgcn_s_setprio(0);                                               \
  } while (0)

__global__ void __launch_bounds__(512, 2) k_gemm2(
    const unsigned short* __restrict__ A2,
    const unsigned short* __restrict__ Wd,
    float* __restrict__ out,
    int k2g, int accum) {
  extern __shared__ char lds[];
  char* As = lds;                   // [2][2][256][64B]
  char* Bs = lds + 65536;
  const int tid = threadIdx.x;
  const int l = tid & 63, wv = tid >> 6;

  // grid 256 = 32y x 8x; 32 blocks per XCD (x fastest)
  const int h = blockIdx.x;
  const int L = (h & 7) * 32 + (h >> 3);
  const int y = L >> 3;
  const int x = L & 7;
  const int bm = y << 8;
  const int bn = x << 8;
  const int wr = wv >> 2, wc = wv & 3;     // 2M x 4N

  const unsigned short* gA = A2 + (size_t)bm * k2g;
  const unsigned short* gB = Wd + (size_t)bn * (NE * FF);

  const int scolE = (((l & 3) ^ ((l >> 3) & 3)) << 3);
  const int fr  = l & 15;
  const int cph = (((l >> 4) ^ ((fr >> 1) & 3)) << 4);
  const int aoff = (wr * 128 + fr) * 64 + cph;
  const int boff = (wc * 64 + fr) * 64 + cph;

  const size_t aOff0 = (size_t)(wv * 16 + (l >> 2)) * k2g + scolE;
  const size_t aOff1 = (size_t)((wv + 8) * 16 + (l >> 2)) * k2g + scolE;
  const size_t bOff0 = (size_t)(wv * 16 + (l >> 2)) * (NE * FF) + scolE;
  const size_t bOff1 = (size_t)((wv + 8) * 16 + (l >> 2)) * (NE * FF) + scolE;

  f32x4 acc[8][4];
  const f32x4 zero = {0.f, 0.f, 0.f, 0.f};
  #pragma unroll
  for (int i = 0; i < 8; ++i) {
    #pragma unroll
    for (int j = 0; j < 4; ++j) acc[i][j] = zero;
  }

  // prologue: (0,0) (0,1) (1,0)
  G2_ST_A(0,  As);
  G2_ST_B(0,  Bs);
  G2_ST_A(32, As + 16384);
  G2_ST_B(32, Bs + 16384);
  G2_ST_A(64, As + 32768);
  G2_ST_B(64, Bs + 32768);
  WAIT8_BAR();

  const int NT = k2g / 64;
  for (int t = 0; t < NT; ++t) {
    const int rs = t & 1, sw = rs ^ 1;
    const int kn1 = ((t + 1 < NT) ? t + 1 : NT - 1) * 64;
    const int kn2 = ((t + 2 < NT) ? t + 2 : NT - 1) * 64;
    G2_ST_A(kn1 + 32, As + sw * 32768 + 16384);
    G2_HALF(rs, 0, G2_ST_B(kn1 + 32, Bs + sw * 32768 + 16384));
    WAIT8_BAR();
    G2_ST_A(kn2, As + rs * 32768);
    G2_HALF(rs, 1, G2_ST_B(kn2, Bs + rs * 32768));
    WAIT8_BAR();
  }

  const int orow = (l >> 4) << 2;
  #pragma unroll
  for (int am = 0; am < 8; ++am) {
    #pragma unroll
    for (int rr = 0; rr < 4; ++rr) {
      const int n = bm + wr * 128 + am * 16 + orow + rr;
      float* op = out + (size_t)n * HD + bn + wc * 64 + fr;
      #pragma unroll
      for (int j = 0; j < 4; ++j) {
        const float v = acc[am][j][rr];
        op[j * 16] = accum ? (op[j * 16] + v) : v;
      }
    }
  }
}

extern "C" void kernel_launch(void* const* d_in, const int* in_sizes, int n_in,
                              void* d_out, int out_size, void* d_ws, size_t ws_size,
                              hipStream_t stream) {
  (void)in_sizes; (void)out_size;
  if (n_in < 5) return;
  const float* x  = (const float*)d_in[0];
  const float* Wr = (const float*)d_in[1];
  const float* Wg = (const float*)d_in[2];
  const float* Wu = (const float*)d_in[3];
  const float* Wd = (const float*)d_in[4];
  float* out  = (float*)d_out;
  float* rout = out + (size_t)N_TOK * HD;

  hipFuncSetAttribute((const void*)k_gemm1, hipFuncAttributeMaxDynamicSharedMemorySize, 131072);
  hipFuncSetAttribute((const void*)k_gemm2, hipFuncAttributeMaxDynamicSharedMemorySize, 131072);

  char* ws = (char*)d_ws;
  const size_t SZ_XB = (size_t)N_TOK * HD * 2;
  const size_t SZ_W  = (size_t)NE * HD * FF * 2;
  unsigned short* xb    = (unsigned short*)(ws);
  unsigned short* Wg_bt = (unsigned short*)(ws + SZ_XB);
  unsigned short* Wu_bt = (unsigned short*)(ws + SZ_XB + SZ_W);
  unsigned short* Wd_bt = (unsigned short*)(ws + SZ_XB + 2 * SZ_W);
  float*          wbuf  = (float*)(ws + SZ_XB + 3 * SZ_W);
  size_t off = SZ_XB + 3 * SZ_W + (size_t)N_TOK * NE * 4;
  int* idxbuf = (int*)(ws + off);  off += (size_t)NE * N_TOK * 4;
  int* cntbuf = (int*)(ws + off);  off += 256;
  const size_t fixed = off;
  unsigned short* A2 = (unsigned short*)(ws + fixed);

  const size_t perE = (size_t)N_TOK * FF * 2;
  int G = 8;
  while (G > 1 && fixed + (size_t)G * perE > ws_size) G >>= 1;

  // weight transposes (fp32 -> bf16 B^T layouts)
  dim3 tb(32, 8);
  k_tconv<<<dim3(FF / 32, HD / 32, NE), tb, 0, stream>>>(
      Wg, Wg_bt, HD, FF, (size_t)HD * FF, (size_t)FF * HD, (size_t)HD);
  k_tconv<<<dim3(FF / 32, HD / 32, NE), tb, 0, stream>>>(
      Wu, Wu_bt, HD, FF, (size_t)HD * FF, (size_t)FF * HD, (size_t)HD);
  k_tconv<<<dim3(HD / 32, FF / 32, NE), tb, 0, stream>>>(
      Wd, Wd_bt, FF, HD, (size_t)FF * HD, (size_t)FF, (size_t)(NE * FF));

  // router (fp32 exact) -> wbuf + d_out router section; also emits xb (bf16)
  k_router<<<N_TOK / 4, 256, 0, stream>>>(x, Wr, wbuf, rout, xb);

  // per-expert token compaction
  k_compact<<<NE, 256, 0, stream>>>(wbuf, idxbuf, cntbuf);

  // expert GEMMs (G experts per pass; accumulate across passes)
  const int k2g = G * FF;
  for (int e0 = 0; e0 < NE; e0 += G) {
    hipMemsetAsync(A2, 0, (size_t)G * perE, stream);   // zero inactive rows
    const int nwg1 = 256 * G;   // per expert: 8 f-blocks x 32 y-blocks
    k_gemm1<<<nwg1, 512, 131072, stream>>>(xb, Wg_bt, Wu_bt, wbuf, idxbuf, cntbuf,
                                           A2, e0, k2g, nwg1);
    k_gemm2<<<(N_TOK / 256) * (HD / 256), 512, 131072, stream>>>(
        A2, Wd_bt + (size_t)e0 * FF, out, k2g, e0 != 0);
  }
}

// Round 9
// 700.660 us; speedup vs baseline: 1.0138x; 1.0138x over previous
//
#include <hip/hip_runtime.h>
#include <hip/hip_bf16.h>

#define N_TOK 8192
#define HD    2048
#define NE    8
#define FF    1024

using f32x4  = __attribute__((ext_vector_type(4))) float;
using bf16x8 = __attribute__((ext_vector_type(8))) __bf16;

#define MFMA16(a, b, c) __builtin_amdgcn_mfma_f32_16x16x32_bf16((a), (b), (c), 0, 0, 0)
#define BARX() do { __builtin_amdgcn_s_barrier(); __builtin_amdgcn_sched_barrier(0); } while (0)
#define VMW(N) asm volatile("s_waitcnt vmcnt(" #N ")" ::: "memory")

__device__ __forceinline__ unsigned short f2bf(float f) {
  unsigned u = __float_as_uint(f);
  u += 0x7FFFu + ((u >> 16) & 1u);   // RTNE (inputs are finite/normal)
  return (unsigned short)(u >> 16);
}

__device__ __forceinline__ void gl_lds16(const void* g, void* l) {
  __builtin_amdgcn_global_load_lds((__attribute__((address_space(1))) void*)g,
                                   (__attribute__((address_space(3))) void*)l,
                                   16, 0, 0);
}

// ---- tiled transpose + convert: in[z][R][C] fp32 -> out[z*out_z + c*ostride + r] bf16 ----
__global__ void k_tconv(const float* __restrict__ in, unsigned short* __restrict__ out,
                        int R, int C, size_t in_z, size_t out_z, size_t ostride) {
  __shared__ float tile[32][33];
  const int z = blockIdx.z;
  const int c0 = blockIdx.x * 32, r0 = blockIdx.y * 32;
  const int tx = threadIdx.x, ty = threadIdx.y;
  const float* ip = in + (size_t)z * in_z;
  unsigned short* op = out + (size_t)z * out_z;
  #pragma unroll
  for (int i = ty; i < 32; i += 8)
    tile[i][tx] = ip[(size_t)(r0 + i) * C + (c0 + tx)];
  __syncthreads();
  #pragma unroll
  for (int i = ty; i < 32; i += 8)
    op[(size_t)(c0 + i) * ostride + (r0 + tx)] = f2bf(tile[tx][i]);
}

// ---- router: w = relu(x @ W_router), fp32 exact; also emits x in bf16. ----
__global__ void k_router(const float* __restrict__ x, const float* __restrict__ Wr,
                         float* __restrict__ w, float* __restrict__ rout,
                         unsigned short* __restrict__ xb) {
  const int lane = threadIdx.x & 63, wv = threadIdx.x >> 6;
  const int n = blockIdx.x * 4 + wv;
  const float* xr = x + (size_t)n * HD + lane * 32;
  unsigned short* xbr = xb + (size_t)n * HD + lane * 32;
  const float* wbase = Wr + (size_t)lane * 32 * NE;
  float acc[8];
  #pragma unroll
  for (int e = 0; e < 8; ++e) acc[e] = 0.f;
  #pragma unroll
  for (int kk = 0; kk < 32; kk += 4) {
    float4 xv = *reinterpret_cast<const float4*>(xr + kk);
    ushort4 o;
    o.x = f2bf(xv.x); o.y = f2bf(xv.y); o.z = f2bf(xv.z); o.w = f2bf(xv.w);
    *reinterpret_cast<ushort4*>(xbr + kk) = o;
    #pragma unroll
    for (int t = 0; t < 4; ++t) {
      const float* wrow = wbase + (kk + t) * 8;
      float4 w0 = *reinterpret_cast<const float4*>(wrow);
      float4 w1 = *reinterpret_cast<const float4*>(wrow + 4);
      float xs = (t == 0) ? xv.x : (t == 1) ? xv.y : (t == 2) ? xv.z : xv.w;
      acc[0] += xs * w0.x; acc[1] += xs * w0.y; acc[2] += xs * w0.z; acc[3] += xs * w0.w;
      acc[4] += xs * w1.x; acc[5] += xs * w1.y; acc[6] += xs * w1.z; acc[7] += xs * w1.w;
    }
  }
  #pragma unroll
  for (int off = 32; off; off >>= 1) {
    #pragma unroll
    for (int e = 0; e < 8; ++e) acc[e] += __shfl_down(acc[e], off);
  }
  if (lane == 0) {
    #pragma unroll
    for (int e = 0; e < 8; ++e) {
      float v = acc[e] > 0.f ? acc[e] : 0.f;
      w[n * 8 + e] = v;
      rout[n * 8 + e] = v;
    }
  }
}

// ---- per-expert stable compaction: idx[e][0..Me) = tokens with w>0, pad to 256-mult ----
__global__ void k_compact(const float* __restrict__ w, int* __restrict__ idx,
                          int* __restrict__ cnt) {
  const int e = blockIdx.x;
  __shared__ int base;
  __shared__ int scan[4];
  if (threadIdx.x == 0) base = 0;
  __syncthreads();
  const int lane = threadIdx.x & 63, wvi = threadIdx.x >> 6;
  for (int c0 = 0; c0 < N_TOK; c0 += 256) {
    const int n = c0 + threadIdx.x;
    const bool act = w[n * 8 + e] > 0.f;
    unsigned long long m = __ballot(act);
    const int pre  = __popcll(m & ((1ull << lane) - 1ull));
    if (lane == 0) scan[wvi] = __popcll(m);
    __syncthreads();
    int woff = 0;
    #pragma unroll
    for (int i = 0; i < 4; ++i) if (i < wvi) woff += scan[i];
    const int tot = scan[0] + scan[1] + scan[2] + scan[3];
    if (act) idx[e * N_TOK + base + woff + pre] = n;
    __syncthreads();
    if (threadIdx.x == 0) base += tot;
    __syncthreads();
  }
  const int M = base;
  if (threadIdx.x == 0) cnt[e] = M;
  const int Mpad = (M + 255) & ~255;
  for (int i = M + threadIdx.x; i < Mpad; i += 256) idx[e * N_TOK + i] = 0;
}

// =======================================================================
// GEMM1: fused gate+up on COMPACTED tokens, 256x128 tile, BK=64.
// m201-style 4-phase schedule: per phase {ds_read subtile, stage one
// 64-row group of tile t+1, barrier, setprio 16-MFMA, [counted vmcnt],
// barrier}. Stage order/tile: [q0,q1,q2,q3,g0,g1,u0,u1]; vmcnt(4) at
// ph1-end (retires u of t), vmcnt(2) at ph3-end (retires q+g of t+1).
// Waves 4M x 2N (64 rows x 64 f-cols, both g,u).
// LDS: A 2x32K @0; Bg 2x16K @64K; Bu 2x16K @96K = 128K.
// =======================================================================
#define G1_MM(p, ACC) do {                                                       \
    __builtin_amdgcn_s_setprio(1);                                               \
    _Pragma("unroll")                                                            \
    for (int j = 0; j < 4; ++j) {                                                \
      ACC[(p)*2][j]   = MFMA16(av_[(p)*2][0],   b_[j][0], ACC[(p)*2][j]);        \
      ACC[(p)*2][j]   = MFMA16(av_[(p)*2][1],   b_[j][1], ACC[(p)*2][j]);        \
      ACC[(p)*2+1][j] = MFMA16(av_[(p)*2+1][0], b_[j][0], ACC[(p)*2+1][j]);      \
      ACC[(p)*2+1][j] = MFMA16(av_[(p)*2+1][1], b_[j][1], ACC[(p)*2+1][j]);      \
    }                                                                            \
    __builtin_amdgcn_s_setprio(0);                                               \
  } while (0)

__global__ void __launch_bounds__(512, 2) k_gemm1(
    const unsigned short* __restrict__ xb,
    const unsigned short* __restrict__ Wg,
    const unsigned short* __restrict__ Wu,
    const float* __restrict__ w,
    const int* __restrict__ idx,
    const int* __restrict__ cnt,
    unsigned short* __restrict__ A2,
    int e0, int k2g, int nwg) {
  extern __shared__ char lds[];
  char* As  = lds;                  // [2][256 rows][64 cols] 32K/slot
  char* Bgs = lds + 65536;          // [2][128][64] 16K/slot
  char* Bus = lds + 98304;
  const int tid = threadIdx.x;
  const int l = tid & 63, wv = tid >> 6;

  // XCD-chunk bijective swizzle; one expert per 256-block chunk, y fastest
  const int h = blockIdx.x;
  const int chunk = nwg >> 3;
  const int L = (h & 7) * chunk + (h >> 3);
  const int eloc = L >> 8;
  const int e = e0 + eloc;
  const int idxq = L & 255;
  const int f = idxq >> 5;                 // 8 f-blocks of 128
  const int y = idxq & 31;                 // 32 y-blocks, fastest
  const int bm = y << 8;
  const int bf = f << 7;
  const int wr = wv >> 1, wc = wv & 1;     // 4M x 2N waves

  const int Me = cnt[e];
  if (bm >= Me) return;
  const int* idxe = idx + e * N_TOK;

  const unsigned short* gBg = Wg + ((size_t)e * FF + bf) * HD;
  const unsigned short* gBu = Wu + ((size_t)e * FF + bf) * HD;

  // stage: thread t -> row t>>3 of a 64-row group, slot t&7, linear LDS dst tid*16
  const int scolE = ((tid & 7) ^ ((tid >> 3) & 7)) << 3;   // elements
  // read: row fr, k-chunk c -> slot c^(fr&7)
  const int fr  = l & 15;
  const int cph0 = (((l >> 4) ^ (l & 7)) << 4);
  const int cph1 = (((4 + (l >> 4)) ^ (l & 7)) << 4);

  // per-thread staging sources
  const unsigned short* aQ[4];
  #pragma unroll
  for (int c = 0; c < 4; ++c)
    aQ[c] = xb + (size_t)idxe[bm + c * 64 + (tid >> 3)] * HD + scolE;
  size_t srcW[2];
  #pragma unroll
  for (int c = 0; c < 2; ++c)
    srcW[c] = (size_t)(c * 64 + (tid >> 3)) * HD + scolE;

  f32x4 ag[4][4], au[4][4];
  const f32x4 zero = {0.f, 0.f, 0.f, 0.f};
  #pragma unroll
  for (int i = 0; i < 4; ++i) {
    #pragma unroll
    for (int j = 0; j < 4; ++j) { ag[i][j] = zero; au[i][j] = zero; }
  }

  // prologue: tile0 in order [q0,q1,q2,q3,g0,g1,u0,u1]; keep u0,u1 in flight
  gl_lds16(aQ[0], As + 0 * 8192 + tid * 16);
  gl_lds16(aQ[1], As + 1 * 8192 + tid * 16);
  gl_lds16(aQ[2], As + 2 * 8192 + tid * 16);
  gl_lds16(aQ[3], As + 3 * 8192 + tid * 16);
  gl_lds16(gBg + srcW[0], Bgs + 0 * 8192 + tid * 16);
  gl_lds16(gBg + srcW[1], Bgs + 1 * 8192 + tid * 16);
  gl_lds16(gBu + srcW[0], Bus + 0 * 8192 + tid * 16);
  gl_lds16(gBu + srcW[1], Bus + 1 * 8192 + tid * 16);
  VMW(2);
  BARX();

  const int NT = HD / 64;   // 32
  for (int t = 0; t < NT; ++t) {
    const int rs = t & 1, sd = rs ^ 1;
    const int kn = ((t + 1 < NT) ? t + 1 : NT - 1) * 64;
    const char* Ar = As + rs * 32768;
    const char* Gr = Bgs + rs * 16384;
    const char* Ur = Bus + rs * 16384;
    char* Ad = As + sd * 32768;
    char* Gd = Bgs + sd * 16384;
    char* Ud = Bus + sd * 16384;
    bf16x8 av_[4][2], b_[4][2];
    // ---- ph0: read A(all) + Bg; stage q0,q1(t+1); MFMA g m0,m1 ----
    {
      const char* Ab_ = Ar + (wr * 64 + fr) * 128;
      #pragma unroll
      for (int m = 0; m < 4; ++m) {
        av_[m][0] = *(const bf16x8*)(Ab_ + m * 2048 + cph0);
        av_[m][1] = *(const bf16x8*)(Ab_ + m * 2048 + cph1);
      }
      const char* Gb_ = Gr + (wc * 64 + fr) * 128;
      #pragma unroll
      for (int j = 0; j < 4; ++j) {
        b_[j][0] = *(const bf16x8*)(Gb_ + j * 2048 + cph0);
        b_[j][1] = *(const bf16x8*)(Gb_ + j * 2048 + cph1);
      }
    }
    gl_lds16(aQ[0] + kn, Ad + 0 * 8192 + tid * 16);
    gl_lds16(aQ[1] + kn, Ad + 1 * 8192 + tid * 16);
    BARX();
    G1_MM(0, ag);
    BARX();
    // ---- ph1: stage q2,q3(t+1); MFMA g m2,m3; vmcnt(4) ----
    gl_lds16(aQ[2] + kn, Ad + 2 * 8192 + tid * 16);
    gl_lds16(aQ[3] + kn, Ad + 3 * 8192 + tid * 16);
    BARX();
    G1_MM(1, ag);
    VMW(4);
    BARX();
    // ---- ph2: read Bu; stage g0,g1(t+1); MFMA u m0,m1 ----
    {
      const char* Ub_ = Ur + (wc * 64 + fr) * 128;
      #pragma unroll
      for (int j = 0; j < 4; ++j) {
        b_[j][0] = *(const bf16x8*)(Ub_ + j * 2048 + cph0);
        b_[j][1] = *(const bf16x8*)(Ub_ + j * 2048 + cph1);
      }
    }
    gl_lds16(gBg + srcW[0] + kn, Gd + 0 * 8192 + tid * 16);
    gl_lds16(gBg + srcW[1] + kn, Gd + 1 * 8192 + tid * 16);
    BARX();
    G1_MM(0, au);
    BARX();
    // ---- ph3: stage u0,u1(t+1); MFMA u m2,m3; vmcnt(2) ----
    gl_lds16(gBu + srcW[0] + kn, Ud + 0 * 8192 + tid * 16);
    gl_lds16(gBu + srcW[1] + kn, Ud + 1 * 8192 + tid * 16);
    BARX();
    G1_MM(1, au);
    VMW(2);
    BARX();
  }

  // epilogue: silu(g)*u*w -> A2 (scattered to original token rows).
  // Padded rows (cm in [Me,Mpad)) rewrite token0's exact value -> benign dup.
  const int orow = (l >> 4) << 2;
  #pragma unroll
  for (int am = 0; am < 4; ++am) {
    #pragma unroll
    for (int rr = 0; rr < 4; ++rr) {
      const int cm = bm + wr * 64 + am * 16 + orow + rr;
      const int n = idxe[cm];
      const float wn = w[n * 8 + e];
      size_t obase = (size_t)n * k2g + (size_t)eloc * FF + bf + wc * 64 + fr;
      #pragma unroll
      for (int j = 0; j < 4; ++j) {
        const float g = ag[am][j][rr];
        const float u = au[am][j][rr];
        const float s = g / (1.f + __expf(-g));
        A2[obase + j * 16] = f2bf(s * u * wn);
      }
    }
  }
}

// =======================================================================
// GEMM2 (dense): out(+)= A2 @ Wd. 256x256 tile, BK=64, waves 2M x 4N
// (128x64/wave). 4-phase m201-style: phase p computes m-frags {2p,2p+1};
// B read fully at ph0, A quarter per phase. Stage order/tile:
// [b0,b1,b2,b3,q0,q2,q1,q3]; vmcnt(4)@ph1-end, vmcnt(2)@ph3-end.
// LDS: A 2x32K @0; B 2x32K @64K = 128K.
// =======================================================================
#define G2_RD_A(p) do {                                                          \
    const char* Ab_ = Ar + (wr * 128 + (p) * 32 + fr) * 128;                     \
    av_[0][0] = *(const bf16x8*)(Ab_ + cph0);                                    \
    av_[0][1] = *(const bf16x8*)(Ab_ + cph1);                                    \
    av_[1][0] = *(const bf16x8*)(Ab_ + 2048 + cph0);                             \
    av_[1][1] = *(const bf16x8*)(Ab_ + 2048 + cph1);                             \
  } while (0)

#define G2_MM(p) do {                                                            \
    __builtin_amdgcn_s_setprio(1);                                               \
    _Pragma("unroll")                                                            \
    for (int j = 0; j < 4; ++j) {                                                \
      acc[(p)*2][j]   = MFMA16(av_[0][0], bv_[j][0], acc[(p)*2][j]);             \
      acc[(p)*2][j]   = MFMA16(av_[0][1], bv_[j][1], acc[(p)*2][j]);             \
      acc[(p)*2+1][j] = MFMA16(av_[1][0], bv_[j][0], acc[(p)*2+1][j]);           \
      acc[(p)*2+1][j] = MFMA16(av_[1][1], bv_[j][1], acc[(p)*2+1][j]);           \
    }                                                                            \
    __builtin_amdgcn_s_setprio(0);                                               \
  } while (0)

__global__ void __launch_bounds__(512, 2) k_gemm2(
    const unsigned short* __restrict__ A2,
    const unsigned short* __restrict__ Wd,
    float* __restrict__ out,
    int k2g, int accum) {
  extern __shared__ char lds[];
  char* As = lds;                   // [2][256][64]
  char* Bs = lds + 65536;
  const int tid = threadIdx.x;
  const int l = tid & 63, wv = tid >> 6;

  // grid 256 = 32y x 8x; per XCD 4y x 8x (x fastest)
  const int h = blockIdx.x;
  const int L = (h & 7) * 32 + (h >> 3);
  const int y = L >> 3;
  const int x = L & 7;
  const int bm = y << 8;
  const int bn = x << 8;
  const int wr = wv >> 2, wc = wv & 3;     // 2M x 4N

  const unsigned short* gA = A2 + (size_t)bm * k2g;
  const unsigned short* gB = Wd + (size_t)bn * (NE * FF);

  const int scolE = ((tid & 7) ^ ((tid >> 3) & 7)) << 3;
  const int fr  = l & 15;
  const int cph0 = (((l >> 4) ^ (l & 7)) << 4);
  const int cph1 = (((4 + (l >> 4)) ^ (l & 7)) << 4);

  size_t srcA[4], srcB[4];
  #pragma unroll
  for (int c = 0; c < 4; ++c) {
    srcA[c] = (size_t)(c * 64 + (tid >> 3)) * k2g + scolE;
    srcB[c] = (size_t)(c * 64 + (tid >> 3)) * (NE * FF) + scolE;
  }

  f32x4 acc[8][4];
  const f32x4 zero = {0.f, 0.f, 0.f, 0.f};
  #pragma unroll
  for (int i = 0; i < 8; ++i) {
    #pragma unroll
    for (int j = 0; j < 4; ++j) acc[i][j] = zero;
  }

  // prologue: tile0 in order [b0,b1,b2,b3,q0,q2,q1,q3]; keep q1,q3 in flight
  gl_lds16(gB + srcB[0], Bs + 0 * 8192 + tid * 16);
  gl_lds16(gB + srcB[1], Bs + 1 * 8192 + tid * 16);
  gl_lds16(gB + srcB[2], Bs + 2 * 8192 + tid * 16);
  gl_lds16(gB + srcB[3], Bs + 3 * 8192 + tid * 16);
  gl_lds16(gA + srcA[0], As + 0 * 8192 + tid * 16);
  gl_lds16(gA + srcA[2], As + 2 * 8192 + tid * 16);
  gl_lds16(gA + srcA[1], As + 1 * 8192 + tid * 16);
  gl_lds16(gA + srcA[3], As + 3 * 8192 + tid * 16);
  VMW(2);
  BARX();

  const int NT = k2g / 64;
  for (int t = 0; t < NT; ++t) {
    const int rs = t & 1, sd = rs ^ 1;
    const int kn = ((t + 1 < NT) ? t + 1 : NT - 1) * 64;
    const char* Ar = As + rs * 32768;
    const char* Br = Bs + rs * 32768;
    char* Ad = As + sd * 32768;
    char* Bd = Bs + sd * 32768;
    bf16x8 bv_[4][2], av_[2][2];
    // ---- ph0: read B(all) + A q-sub0; stage b0,b1(t+1); MFMA m0,m1 ----
    {
      const char* Bb_ = Br + (wc * 64 + fr) * 128;
      #pragma unroll
      for (int j = 0; j < 4; ++j) {
        bv_[j][0] = *(const bf16x8*)(Bb_ + j * 2048 + cph0);
        bv_[j][1] = *(const bf16x8*)(Bb_ + j * 2048 + cph1);
      }
    }
    G2_RD_A(0);
    gl_lds16(gB + srcB[0] + kn, Bd + 0 * 8192 + tid * 16);
    gl_lds16(gB + srcB[1] + kn, Bd + 1 * 8192 + tid * 16);
    BARX();
    G2_MM(0);
    BARX();
    // ---- ph1: read A sub1; stage b2,b3(t+1); MFMA m2,m3; vmcnt(4) ----
    G2_RD_A(1);
    gl_lds16(gB + srcB[2] + kn, Bd + 2 * 8192 + tid * 16);
    gl_lds16(gB + srcB[3] + kn, Bd + 3 * 8192 + tid * 16);
    BARX();
    G2_MM(1);
    VMW(4);
    BARX();
    // ---- ph2: read A sub2; stage q0,q2(t+1); MFMA m4,m5 ----
    G2_RD_A(2);
    gl_lds16(gA + srcA[0] + kn, Ad + 0 * 8192 + tid * 16);
    gl_lds16(gA + srcA[2] + kn, Ad + 2 * 8192 + tid * 16);
    BARX();
    G2_MM(2);
    BARX();
    // ---- ph3: read A sub3; stage q1,q3(t+1); MFMA m6,m7; vmcnt(2) ----
    G2_RD_A(3);
    gl_lds16(gA + srcA[1] + kn, Ad + 1 * 8192 + tid * 16);
    gl_lds16(gA + srcA[3] + kn, Ad + 3 * 8192 + tid * 16);
    BARX();
    G2_MM(3);
    VMW(2);
    BARX();
  }

  const int orow = (l >> 4) << 2;
  #pragma unroll
  for (int am = 0; am < 8; ++am) {
    #pragma unroll
    for (int rr = 0; rr < 4; ++rr) {
      const int n = bm + wr * 128 + am * 16 + orow + rr;
      float* op = out + (size_t)n * HD + bn + wc * 64 + fr;
      #pragma unroll
      for (int j = 0; j < 4; ++j) {
        const float v = acc[am][j][rr];
        op[j * 16] = accum ? (op[j * 16] + v) : v;
      }
    }
  }
}

extern "C" void kernel_launch(void* const* d_in, const int* in_sizes, int n_in,
                              void* d_out, int out_size, void* d_ws, size_t ws_size,
                              hipStream_t stream) {
  (void)in_sizes; (void)out_size;
  if (n_in < 5) return;
  const float* x  = (const float*)d_in[0];
  const float* Wr = (const float*)d_in[1];
  const float* Wg = (const float*)d_in[2];
  const float* Wu = (const float*)d_in[3];
  const float* Wd = (const float*)d_in[4];
  float* out  = (float*)d_out;
  float* rout = out + (size_t)N_TOK * HD;

  hipFuncSetAttribute((const void*)k_gemm1, hipFuncAttributeMaxDynamicSharedMemorySize, 131072);
  hipFuncSetAttribute((const void*)k_gemm2, hipFuncAttributeMaxDynamicSharedMemorySize, 131072);

  char* ws = (char*)d_ws;
  const size_t SZ_XB = (size_t)N_TOK * HD * 2;
  const size_t SZ_W  = (size_t)NE * HD * FF * 2;
  unsigned short* xb    = (unsigned short*)(ws);
  unsigned short* Wg_bt = (unsigned short*)(ws + SZ_XB);
  unsigned short* Wu_bt = (unsigned short*)(ws + SZ_XB + SZ_W);
  unsigned short* Wd_bt = (unsigned short*)(ws + SZ_XB + 2 * SZ_W);
  float*          wbuf  = (float*)(ws + SZ_XB + 3 * SZ_W);
  size_t off = SZ_XB + 3 * SZ_W + (size_t)N_TOK * NE * 4;
  int* idxbuf = (int*)(ws + off);  off += (size_t)NE * N_TOK * 4;
  int* cntbuf = (int*)(ws + off);  off += 256;
  const size_t fixed = off;
  unsigned short* A2 = (unsigned short*)(ws + fixed);

  const size_t perE = (size_t)N_TOK * FF * 2;
  int G = 8;
  while (G > 1 && fixed + (size_t)G * perE > ws_size) G >>= 1;

  // weight transposes (fp32 -> bf16 B^T layouts)
  dim3 tb(32, 8);
  k_tconv<<<dim3(FF / 32, HD / 32, NE), tb, 0, stream>>>(
      Wg, Wg_bt, HD, FF, (size_t)HD * FF, (size_t)FF * HD, (size_t)HD);
  k_tconv<<<dim3(FF / 32, HD / 32, NE), tb, 0, stream>>>(
      Wu, Wu_bt, HD, FF, (size_t)HD * FF, (size_t)FF * HD, (size_t)HD);
  k_tconv<<<dim3(HD / 32, FF / 32, NE), tb, 0, stream>>>(
      Wd, Wd_bt, FF, HD, (size_t)FF * HD, (size_t)FF, (size_t)(NE * FF));

  // router (fp32 exact) -> wbuf + d_out router section; also emits xb (bf16)
  k_router<<<N_TOK / 4, 256, 0, stream>>>(x, Wr, wbuf, rout, xb);

  // per-expert token compaction
  k_compact<<<NE, 256, 0, stream>>>(wbuf, idxbuf, cntbuf);

  // expert GEMMs (G experts per pass; accumulate across passes)
  const int k2g = G * FF;
  for (int e0 = 0; e0 < NE; e0 += G) {
    hipMemsetAsync(A2, 0, (size_t)G * perE, stream);   // zero inactive rows
    const int nwg1 = 256 * G;   // per expert: 8 f-blocks x 32 y-blocks
    k_gemm1<<<nwg1, 512, 131072, stream>>>(xb, Wg_bt, Wu_bt, wbuf, idxbuf, cntbuf,
                                           A2, e0, k2g, nwg1);
    k_gemm2<<<(N_TOK / 256) * (HD / 256), 512, 131072, stream>>>(
        A2, Wd_bt + (size_t)e0 * FF, out, k2g, e0 != 0);
  }
}

// Round 10
// 699.278 us; speedup vs baseline: 1.0158x; 1.0020x over previous
//
#include <hip/hip_runtime.h>
#include <hip/hip_bf16.h>

#define N_TOK 8192
#define HD    2048
#define NE    8
#define FF    1024

using f32x4  = __attribute__((ext_vector_type(4))) float;
using bf16x8 = __attribute__((ext_vector_type(8))) __bf16;

__device__ __forceinline__ unsigned short f2bf(float f) {
  unsigned u = __float_as_uint(f);
  u += 0x7FFFu + ((u >> 16) & 1u);   // RTNE (inputs are finite/normal)
  return (unsigned short)(u >> 16);
}

__device__ __forceinline__ void gl_lds16(const void* g, void* l) {
  __builtin_amdgcn_global_load_lds((__attribute__((address_space(1))) void*)g,
                                   (__attribute__((address_space(3))) void*)l,
                                   16, 0, 0);
}

// Stage a 256-row x 64-col bf16 tile (32KB): 4 calls/thread, pre-swizzled global src.
__device__ __forceinline__ void stage256(const unsigned short* g, size_t lda, int k0,
                                         char* slotbase, int wv, int sr8, int scol) {
  #pragma unroll
  for (int c = 0; c < 4; ++c) {
    const int grp = c * 8 + wv;
    gl_lds16(g + (size_t)(grp * 8 + sr8) * lda + k0 + scol, slotbase + grp * 1024);
  }
}
// indexed variant: per-thread row base pointers (compacted token gather)
__device__ __forceinline__ void stage256i(const unsigned short* const aP[4], int k0,
                                          char* slotbase, int wv) {
  #pragma unroll
  for (int c = 0; c < 4; ++c) {
    const int grp = c * 8 + wv;
    gl_lds16(aP[c] + k0, slotbase + grp * 1024);
  }
}
// 128-row tile (16KB): 2 calls/thread.
__device__ __forceinline__ void stage128(const unsigned short* g, size_t lda, int k0,
                                         char* slotbase, int wv, int sr8, int scol) {
  #pragma unroll
  for (int c = 0; c < 2; ++c) {
    const int grp = c * 8 + wv;
    gl_lds16(g + (size_t)(grp * 8 + sr8) * lda + k0 + scol, slotbase + grp * 1024);
  }
}

// ---- tiled transpose + convert: in[z][R][C] fp32 -> out[z*out_z + c*ostride + r] bf16 ----
__global__ void k_tconv(const float* __restrict__ in, unsigned short* __restrict__ out,
                        int R, int C, size_t in_z, size_t out_z, size_t ostride) {
  __shared__ float tile[32][33];
  const int z = blockIdx.z;
  const int c0 = blockIdx.x * 32, r0 = blockIdx.y * 32;
  const int tx = threadIdx.x, ty = threadIdx.y;
  const float* ip = in + (size_t)z * in_z;
  unsigned short* op = out + (size_t)z * out_z;
  #pragma unroll
  for (int i = ty; i < 32; i += 8)
    tile[i][tx] = ip[(size_t)(r0 + i) * C + (c0 + tx)];
  __syncthreads();
  #pragma unroll
  for (int i = ty; i < 32; i += 8)
    op[(size_t)(c0 + i) * ostride + (r0 + tx)] = f2bf(tile[tx][i]);
}

// ---- router: w = relu(x @ W_router), fp32 exact; also emits x in bf16. ----
__global__ void k_router(const float* __restrict__ x, const float* __restrict__ Wr,
                         float* __restrict__ w, float* __restrict__ rout,
                         unsigned short* __restrict__ xb) {
  const int lane = threadIdx.x & 63, wv = threadIdx.x >> 6;
  const int n = blockIdx.x * 4 + wv;
  const float* xr = x + (size_t)n * HD + lane * 32;
  unsigned short* xbr = xb + (size_t)n * HD + lane * 32;
  const float* wbase = Wr + (size_t)lane * 32 * NE;
  float acc[8];
  #pragma unroll
  for (int e = 0; e < 8; ++e) acc[e] = 0.f;
  #pragma unroll
  for (int kk = 0; kk < 32; kk += 4) {
    float4 xv = *reinterpret_cast<const float4*>(xr + kk);
    ushort4 o;
    o.x = f2bf(xv.x); o.y = f2bf(xv.y); o.z = f2bf(xv.z); o.w = f2bf(xv.w);
    *reinterpret_cast<ushort4*>(xbr + kk) = o;
    #pragma unroll
    for (int t = 0; t < 4; ++t) {
      const float* wrow = wbase + (kk + t) * 8;
      float4 w0 = *reinterpret_cast<const float4*>(wrow);
      float4 w1 = *reinterpret_cast<const float4*>(wrow + 4);
      float xs = (t == 0) ? xv.x : (t == 1) ? xv.y : (t == 2) ? xv.z : xv.w;
      acc[0] += xs * w0.x; acc[1] += xs * w0.y; acc[2] += xs * w0.z; acc[3] += xs * w0.w;
      acc[4] += xs * w1.x; acc[5] += xs * w1.y; acc[6] += xs * w1.z; acc[7] += xs * w1.w;
    }
  }
  #pragma unroll
  for (int off = 32; off; off >>= 1) {
    #pragma unroll
    for (int e = 0; e < 8; ++e) acc[e] += __shfl_down(acc[e], off);
  }
  if (lane == 0) {
    #pragma unroll
    for (int e = 0; e < 8; ++e) {
      float v = acc[e] > 0.f ? acc[e] : 0.f;
      w[n * 8 + e] = v;
      rout[n * 8 + e] = v;
    }
  }
}

// ---- per-expert stable compaction + inverse map rev[n][e]=cm or -1 ----
__global__ void k_compact(const float* __restrict__ w, int* __restrict__ idx,
                          int* __restrict__ rev, int* __restrict__ cnt) {
  const int e = blockIdx.x;
  __shared__ int base;
  __shared__ int scan[4];
  if (threadIdx.x == 0) base = 0;
  __syncthreads();
  const int lane = threadIdx.x & 63, wvi = threadIdx.x >> 6;
  for (int c0 = 0; c0 < N_TOK; c0 += 256) {
    const int n = c0 + threadIdx.x;
    const bool act = w[n * 8 + e] > 0.f;
    unsigned long long m = __ballot(act);
    const int pre  = __popcll(m & ((1ull << lane) - 1ull));
    if (lane == 0) scan[wvi] = __popcll(m);
    __syncthreads();
    int woff = 0;
    #pragma unroll
    for (int i = 0; i < 4; ++i) if (i < wvi) woff += scan[i];
    const int tot = scan[0] + scan[1] + scan[2] + scan[3];
    const int pos = base + woff + pre;
    if (act) idx[e * N_TOK + pos] = n;
    rev[n * NE + e] = act ? pos : -1;
    __syncthreads();
    if (threadIdx.x == 0) base += tot;
    __syncthreads();
  }
  const int M = base;
  if (threadIdx.x == 0) cnt[e] = M;
  const int Mpad = (M + 255) & ~255;
  for (int i = M + threadIdx.x; i < Mpad; i += 256) idx[e * N_TOK + i] = 0;
}

// =======================================================================
// GEMM1: fused gate+up on COMPACTED tokens, 256x128 tile, BK=64,
// 2-slot double-buffer, T2 swizzle, vmcnt(0)+1-barrier per iter (round-7
// proven). Epilogue silu(g)*u*w -> A2: scattered (dense) or compacted.
// =======================================================================
#define G1_PHASE(cpK) do {                                                       \
    const char* Ab_ = As + rs * 32768 + (wr * 64) * 128 + rb;                    \
    const char* Bg_ = Bgs + rs * 16384 + (wc * 64) * 128 + rb;                   \
    const char* Bu_ = Bus + rs * 16384 + (wc * 64) * 128 + rb;                   \
    bf16x8 av_[4], bg_[4], bu_[4];                                               \
    _Pragma("unroll")                                                            \
    for (int i = 0; i < 4; ++i) av_[i] = *(const bf16x8*)(Ab_ + i * 2048 + (cpK)); \
    _Pragma("unroll")                                                            \
    for (int j = 0; j < 4; ++j) {                                                \
      bg_[j] = *(const bf16x8*)(Bg_ + j * 2048 + (cpK));                         \
      bu_[j] = *(const bf16x8*)(Bu_ + j * 2048 + (cpK));                         \
    }                                                                            \
    __builtin_amdgcn_s_setprio(1);                                               \
    _Pragma("unroll")                                                            \
    for (int i = 0; i < 4; ++i) {                                                \
      _Pragma("unroll")                                                          \
      for (int j = 0; j < 4; ++j) {                                              \
        ag[i][j] = __builtin_amdgcn_mfma_f32_16x16x32_bf16(av_[i], bg_[j], ag[i][j], 0,0,0); \
        au[i][j] = __builtin_amdgcn_mfma_f32_16x16x32_bf16(av_[i], bu_[j], au[i][j], 0,0,0); \
      }                                                                          \
    }                                                                            \
    __builtin_amdgcn_s_setprio(0);                                               \
  } while (0)

__global__ void __launch_bounds__(512, 2) k_gemm1(
    const unsigned short* __restrict__ xb,
    const unsigned short* __restrict__ Wg,
    const unsigned short* __restrict__ Wu,
    const float* __restrict__ w,
    const int* __restrict__ idx,
    const int* __restrict__ cnt,
    unsigned short* __restrict__ A2,
    int e0, int k2g, int nwg, int compacted) {
  extern __shared__ char lds[];
  char* As  = lds;                  // 2 x 32768 = 65536
  char* Bgs = lds + 65536;          // 2 x 16384
  char* Bus = lds + 98304;          // 2 x 16384  (total 131072)
  const int tid = threadIdx.x;
  const int l = tid & 63, wv = tid >> 6;

  // XCD-chunk bijective swizzle; 256 blocks/expert = 8f x 32y, 2f x 8y sub-chunks
  const int h = blockIdx.x;
  const int chunk = nwg >> 3;
  const int L = (h & 7) * chunk + (h >> 3);
  const int eloc = L >> 8;                 // 256 blocks/expert
  const int e = e0 + eloc;
  const int idxq = L & 255;
  const int sub = idxq >> 5;
  const int f = ((sub & 1) << 2) | ((idxq >> 3) & 3);
  const int y = ((sub >> 1) << 3) | (idxq & 7);
  const int bm = y << 8;                   // 256-row tile (compacted space)
  const int bf = f << 7;                   // 128-col f tile
  const int wr = wv >> 1, wc = wv & 1;     // 4M x 2N waves

  const int Me = cnt[e];
  if (bm >= Me) return;
  const int* idxe = idx + e * N_TOK;

  const unsigned short* gBg = Wg + ((size_t)e * FF + bf) * HD;
  const unsigned short* gBu = Wu + ((size_t)e * FF + bf) * HD;

  // staging: pre-swizzled global source, linear LDS dest (rule #21)
  const int sr8  = l >> 3;
  const int scol = ((l & 7) ^ sr8) << 3;   // elements
  // frag reads: same involution on the read side
  const int fr  = l & 15;
  const int rb  = fr << 7;                 // row byte (128B rows)
  const int kc  = (l >> 4) << 4;
  const int swz = (l & 7) << 4;
  const int cp0 = kc ^ swz;
  const int cp1 = (64 + kc) ^ swz;

  // per-thread A row base pointers (gathered via compacted index; block-constant)
  const unsigned short* aP[4];
  #pragma unroll
  for (int c = 0; c < 4; ++c)
    aP[c] = xb + (size_t)idxe[bm + (c * 8 + wv) * 8 + sr8] * HD + scol;

  f32x4 ag[4][4], au[4][4];
  const f32x4 zero = {0.f, 0.f, 0.f, 0.f};
  #pragma unroll
  for (int i = 0; i < 4; ++i) {
    #pragma unroll
    for (int j = 0; j < 4; ++j) { ag[i][j] = zero; au[i][j] = zero; }
  }

  // prologue: tile 0 into slot 0
  stage256i(aP, 0, As, wv);
  stage128(gBg, HD, 0, Bgs, wv, sr8, scol);
  stage128(gBu, HD, 0, Bus, wv, sr8, scol);
  asm volatile("s_waitcnt vmcnt(0)" ::: "memory");
  __builtin_amdgcn_s_barrier();
  __builtin_amdgcn_sched_barrier(0);

  const int NT = HD / 64;   // 32
  for (int t = 0; t < NT; ++t) {
    const int tn = (t + 1 < NT) ? t + 1 : NT - 1;
    const int sw = (t + 1) & 1;
    const int rs = t & 1;
    stage128(gBg, HD, tn * 64, Bgs + sw * 16384, wv, sr8, scol);
    stage128(gBu, HD, tn * 64, Bus + sw * 16384, wv, sr8, scol);
    G1_PHASE(cp0);
    stage256i(aP, tn * 64, As + sw * 32768, wv);
    G1_PHASE(cp1);
    asm volatile("s_waitcnt vmcnt(0)" ::: "memory");
    __builtin_amdgcn_s_barrier();
    __builtin_amdgcn_sched_barrier(0);
  }

  // epilogue: silu(g)*u*w -> A2.
  // compacted: A2c[eloc][cm][FF]; dense: scatter to token rows (benign dups on pad).
  const int orow = (l >> 4) << 2;
  #pragma unroll
  for (int am = 0; am < 4; ++am) {
    #pragma unroll
    for (int rr = 0; rr < 4; ++rr) {
      const int cm = bm + wr * 64 + am * 16 + orow + rr;
      const int n = idxe[cm];
      const float wn = w[n * 8 + e];
      size_t obase;
      if (compacted)
        obase = (size_t)eloc * N_TOK * FF + (size_t)cm * FF + bf + wc * 64 + fr;
      else
        obase = (size_t)n * k2g + (size_t)eloc * FF + bf + wc * 64 + fr;
      #pragma unroll
      for (int j = 0; j < 4; ++j) {
        const float g = ag[am][j][rr];
        const float u = au[am][j][rr];
        const float s = g / (1.f + __expf(-g));
        A2[obase + j * 16] = f2bf(s * u * wn);
      }
    }
  }
}

// =======================================================================
// GEMM2 (dense): out(+)= A2 @ Wd. 256x256 tile, BK=64, waves 2M x 4N
// (per-wave 128x64). 2-slot dbuf, vmcnt(0)+1 barrier. (round-7 proven)
// =======================================================================
#define G2_PHASE(cpK) do {                                                       \
    const char* Ab_ = As + rs * 32768 + (wr * 128) * 128 + rb;                   \
    const char* Bb_ = Bs + rs * 32768 + (wc * 64) * 128 + rb;                    \
    bf16x8 av_[8], bv_[4];                                                       \
    _Pragma("unroll")                                                            \
    for (int i = 0; i < 8; ++i) av_[i] = *(const bf16x8*)(Ab_ + i * 2048 + (cpK)); \
    _Pragma("unroll")                                                            \
    for (int j = 0; j < 4; ++j) bv_[j] = *(const bf16x8*)(Bb_ + j * 2048 + (cpK)); \
    __builtin_amdgcn_s_setprio(1);                                               \
    _Pragma("unroll")                                                            \
    for (int i = 0; i < 8; ++i) {                                                \
      _Pragma("unroll")                                                          \
      for (int j = 0; j < 4; ++j)                                                \
        acc[i][j] = __builtin_amdgcn_mfma_f32_16x16x32_bf16(av_[i], bv_[j], acc[i][j], 0,0,0); \
    }                                                                            \
    __builtin_amdgcn_s_setprio(0);                                               \
  } while (0)

__global__ void __launch_bounds__(512, 2) k_gemm2(
    const unsigned short* __restrict__ A2,
    const unsigned short* __restrict__ Wd,
    float* __restrict__ out,
    int k2g, int accum) {
  extern __shared__ char lds[];
  char* As = lds;                   // 2 x 32768
  char* Bs = lds + 65536;           // 2 x 32768 (total 131072)
  const int tid = threadIdx.x;
  const int l = tid & 63, wv = tid >> 6;

  const int h = blockIdx.x;
  const int L = (h & 7) * 32 + (h >> 3);
  const int y = L >> 3;                    // 32 m-blocks
  const int x = L & 7;                     // 8 n-blocks
  const int bm = y << 8;
  const int bn = x << 8;
  const int wr = wv >> 2, wc = wv & 3;     // 2M x 4N

  const unsigned short* gA = A2 + (size_t)bm * k2g;
  const unsigned short* gB = Wd + (size_t)bn * (NE * FF);

  const int sr8  = l >> 3;
  const int scol = ((l & 7) ^ sr8) << 3;
  const int fr  = l & 15;
  const int rb  = fr << 7;
  const int kc  = (l >> 4) << 4;
  const int swz = (l & 7) << 4;
  const int cp0 = kc ^ swz;
  const int cp1 = (64 + kc) ^ swz;

  f32x4 acc[8][4];
  const f32x4 zero = {0.f, 0.f, 0.f, 0.f};
  #pragma unroll
  for (int i = 0; i < 8; ++i) {
    #pragma unroll
    for (int j = 0; j < 4; ++j) acc[i][j] = zero;
  }

  stage256(gA, k2g, 0, As, wv, sr8, scol);
  stage256(gB, NE * FF, 0, Bs, wv, sr8, scol);
  asm volatile("s_waitcnt vmcnt(0)" ::: "memory");
  __builtin_amdgcn_s_barrier();
  __builtin_amdgcn_sched_barrier(0);

  const int NT = k2g / 64;
  for (int t = 0; t < NT; ++t) {
    const int tn = (t + 1 < NT) ? t + 1 : NT - 1;
    const int sw = (t + 1) & 1;
    const int rs = t & 1;
    stage256(gB, NE * FF, tn * 64, Bs + sw * 32768, wv, sr8, scol);
    G2_PHASE(cp0);
    stage256(gA, k2g, tn * 64, As + sw * 32768, wv, sr8, scol);
    G2_PHASE(cp1);
    asm volatile("s_waitcnt vmcnt(0)" ::: "memory");
    __builtin_amdgcn_s_barrier();
    __builtin_amdgcn_sched_barrier(0);
  }

  const int orow = (l >> 4) << 2;
  #pragma unroll
  for (int am = 0; am < 8; ++am) {
    #pragma unroll
    for (int rr = 0; rr < 4; ++rr) {
      const int n = bm + wr * 128 + am * 16 + orow + rr;
      float* op = out + (size_t)n * HD + bn + wc * 64 + fr;
      #pragma unroll
      for (int j = 0; j < 4; ++j) {
        const float v = acc[am][j][rr];
        op[j * 16] = accum ? (op[j * 16] + v) : v;
      }
    }
  }
}

// =======================================================================
// GEMM2s (sparse): per-expert compacted A2c[e][cm][FF] @ Wd_e -> compacted
// outc[e][cm][H] fp32 (plain stores, exclusive rows). Same proven pipeline,
// K=FF=1024 (NT=16). Grid 2048 = 8e x (8x x 32y), XCD-chunked per expert.
// =======================================================================
__global__ void __launch_bounds__(512, 2) k_gemm2s(
    const unsigned short* __restrict__ A2c,
    const unsigned short* __restrict__ Wd,
    const int* __restrict__ cnt,
    float* __restrict__ outc) {
  extern __shared__ char lds[];
  char* As = lds;                   // 2 x 32768
  char* Bs = lds + 65536;           // 2 x 32768
  const int tid = threadIdx.x;
  const int l = tid & 63, wv = tid >> 6;

  const int h = blockIdx.x;
  const int L = (h & 7) * 256 + (h >> 3);  // nwg 2048, chunk 256
  const int eloc = L >> 8;                 // expert
  const int idxq = L & 255;
  const int x = idxq >> 5;                 // 8 n-blocks
  const int y = idxq & 31;                 // 32 m-blocks, fastest
  const int bm = y << 8;
  const int bn = x << 8;
  const int wr = wv >> 2, wc = wv & 3;     // 2M x 4N

  const int Me = cnt[eloc];
  if (bm >= Me) return;

  const unsigned short* gA = A2c + (size_t)eloc * N_TOK * FF + (size_t)bm * FF;
  const unsigned short* gB = Wd + (size_t)bn * (NE * FF) + (size_t)eloc * FF;

  const int sr8  = l >> 3;
  const int scol = ((l & 7) ^ sr8) << 3;
  const int fr  = l & 15;
  const int rb  = fr << 7;
  const int kc  = (l >> 4) << 4;
  const int swz = (l & 7) << 4;
  const int cp0 = kc ^ swz;
  const int cp1 = (64 + kc) ^ swz;

  f32x4 acc[8][4];
  const f32x4 zero = {0.f, 0.f, 0.f, 0.f};
  #pragma unroll
  for (int i = 0; i < 8; ++i) {
    #pragma unroll
    for (int j = 0; j < 4; ++j) acc[i][j] = zero;
  }

  stage256(gA, FF, 0, As, wv, sr8, scol);
  stage256(gB, NE * FF, 0, Bs, wv, sr8, scol);
  asm volatile("s_waitcnt vmcnt(0)" ::: "memory");
  __builtin_amdgcn_s_barrier();
  __builtin_amdgcn_sched_barrier(0);

  const int NT = FF / 64;   // 16
  for (int t = 0; t < NT; ++t) {
    const int tn = (t + 1 < NT) ? t + 1 : NT - 1;
    const int sw = (t + 1) & 1;
    const int rs = t & 1;
    stage256(gB, NE * FF, tn * 64, Bs + sw * 32768, wv, sr8, scol);
    G2_PHASE(cp0);
    stage256(gA, FF, tn * 64, As + sw * 32768, wv, sr8, scol);
    G2_PHASE(cp1);
    asm volatile("s_waitcnt vmcnt(0)" ::: "memory");
    __builtin_amdgcn_s_barrier();
    __builtin_amdgcn_sched_barrier(0);
  }

  // plain stores to compacted outc (padded rows written but never gathered)
  float* oce = outc + (size_t)eloc * N_TOK * HD;
  const int orow = (l >> 4) << 2;
  #pragma unroll
  for (int am = 0; am < 8; ++am) {
    #pragma unroll
    for (int rr = 0; rr < 4; ++rr) {
      const int cm = bm + wr * 128 + am * 16 + orow + rr;
      float* op = oce + (size_t)cm * HD + bn + wc * 64 + fr;
      #pragma unroll
      for (int j = 0; j < 4; ++j) op[j * 16] = acc[am][j][rr];
    }
  }
}

// ---- gather: out[n] = sum over active experts of outc[e][rev[n][e]] ----
__global__ void k_gather(const float* __restrict__ outc, const int* __restrict__ rev,
                         float* __restrict__ out) {
  const int n = blockIdx.x;
  const int h0 = threadIdx.x * 8;
  float4 a0 = {0.f, 0.f, 0.f, 0.f}, a1 = {0.f, 0.f, 0.f, 0.f};
  #pragma unroll
  for (int e = 0; e < NE; ++e) {
    const int cm = rev[n * NE + e];
    if (cm >= 0) {
      const float4* p = reinterpret_cast<const float4*>(
          outc + (size_t)e * N_TOK * HD + (size_t)cm * HD + h0);
      float4 v0 = p[0], v1 = p[1];
      a0.x += v0.x; a0.y += v0.y; a0.z += v0.z; a0.w += v0.w;
      a1.x += v1.x; a1.y += v1.y; a1.z += v1.z; a1.w += v1.w;
    }
  }
  float4* op = reinterpret_cast<float4*>(out + (size_t)n * HD + h0);
  op[0] = a0; op[1] = a1;
}

extern "C" void kernel_launch(void* const* d_in, const int* in_sizes, int n_in,
                              void* d_out, int out_size, void* d_ws, size_t ws_size,
                              hipStream_t stream) {
  (void)in_sizes; (void)out_size;
  if (n_in < 5) return;
  const float* x  = (const float*)d_in[0];
  const float* Wr = (const float*)d_in[1];
  const float* Wg = (const float*)d_in[2];
  const float* Wu = (const float*)d_in[3];
  const float* Wd = (const float*)d_in[4];
  float* out  = (float*)d_out;
  float* rout = out + (size_t)N_TOK * HD;

  hipFuncSetAttribute((const void*)k_gemm1,  hipFuncAttributeMaxDynamicSharedMemorySize, 131072);
  hipFuncSetAttribute((const void*)k_gemm2,  hipFuncAttributeMaxDynamicSharedMemorySize, 131072);
  hipFuncSetAttribute((const void*)k_gemm2s, hipFuncAttributeMaxDynamicSharedMemorySize, 131072);

  char* ws = (char*)d_ws;
  const size_t SZ_XB = (size_t)N_TOK * HD * 2;
  const size_t SZ_W  = (size_t)NE * HD * FF * 2;
  unsigned short* xb    = (unsigned short*)(ws);
  unsigned short* Wg_bt = (unsigned short*)(ws + SZ_XB);
  unsigned short* Wu_bt = (unsigned short*)(ws + SZ_XB + SZ_W);
  unsigned short* Wd_bt = (unsigned short*)(ws + SZ_XB + 2 * SZ_W);
  float*          wbuf  = (float*)(ws + SZ_XB + 3 * SZ_W);
  size_t off = SZ_XB + 3 * SZ_W + (size_t)N_TOK * NE * 4;
  int* idxbuf = (int*)(ws + off);  off += (size_t)NE * N_TOK * 4;
  int* revbuf = (int*)(ws + off);  off += (size_t)NE * N_TOK * 4;
  int* cntbuf = (int*)(ws + off);  off += 256;
  const size_t fixed = off;
  unsigned short* A2 = (unsigned short*)(ws + fixed);

  const size_t perE = (size_t)N_TOK * FF * 2;          // 16.8 MB per expert A2 slab
  const size_t SZ_A2   = (size_t)NE * perE;            // 134 MB
  const size_t SZ_OUTC = (size_t)NE * N_TOK * HD * 4;  // 537 MB (worst-case)
  float* outc = (float*)(ws + fixed + SZ_A2);

  const bool sparse2 = (ws_size >= fixed + SZ_A2 + SZ_OUTC);

  // weight transposes (fp32 -> bf16 B^T layouts)
  dim3 tb(32, 8);
  k_tconv<<<dim3(FF / 32, HD / 32, NE), tb, 0, stream>>>(
      Wg, Wg_bt, HD, FF, (size_t)HD * FF, (size_t)FF * HD, (size_t)HD);
  k_tconv<<<dim3(FF / 32, HD / 32, NE), tb, 0, stream>>>(
      Wu, Wu_bt, HD, FF, (size_t)HD * FF, (size_t)FF * HD, (size_t)HD);
  k_tconv<<<dim3(HD / 32, FF / 32, NE), tb, 0, stream>>>(
      Wd, Wd_bt, FF, HD, (size_t)FF * HD, (size_t)FF, (size_t)(NE * FF));

  // router (fp32 exact) -> wbuf + d_out router section; also emits xb (bf16)
  k_router<<<N_TOK / 4, 256, 0, stream>>>(x, Wr, wbuf, rout, xb);

  // per-expert token compaction (+ inverse map)
  k_compact<<<NE, 256, 0, stream>>>(wbuf, idxbuf, revbuf, cntbuf);

  if (sparse2) {
    // sparse path: compacted A2c -> per-expert gemm2 -> gather (no atomics)
    const int nwg1 = 256 * NE;   // 2048
    k_gemm1<<<nwg1, 512, 131072, stream>>>(xb, Wg_bt, Wu_bt, wbuf, idxbuf, cntbuf,
                                           A2, 0, NE * FF, nwg1, 1);
    k_gemm2s<<<2048, 512, 131072, stream>>>(A2, Wd_bt, cntbuf, outc);
    k_gather<<<N_TOK, 256, 0, stream>>>(outc, revbuf, out);
  } else {
    // dense fallback (round-7 proven)
    int G = 8;
    while (G > 1 && fixed + (size_t)G * perE > ws_size) G >>= 1;
    const int k2g = G * FF;
    for (int e0 = 0; e0 < NE; e0 += G) {
      hipMemsetAsync(A2, 0, (size_t)G * perE, stream);   // zero inactive rows
      const int nwg1 = 256 * G;
      k_gemm1<<<nwg1, 512, 131072, stream>>>(xb, Wg_bt, Wu_bt, wbuf, idxbuf, cntbuf,
                                             A2, e0, k2g, nwg1, 0);
      k_gemm2<<<(N_TOK / 256) * (HD / 256), 512, 131072, stream>>>(
          A2, Wd_bt + (size_t)e0 * FF, out, k2g, e0 != 0);
    }
  }
}